// Round 1
// baseline (238.741 us; speedup 1.0000x reference)
//
#include <hip/hip_runtime.h>
#include <hip/hip_bf16.h>

#define NROWS 4096
#define IDIM  256
#define GDIM  64
#define ODIM  512
#define KDIM  (IDIM * GDIM)   // 16384 per trig branch

typedef __attribute__((ext_vector_type(8))) short bhalf8;  // 8 bf16 bit patterns
typedef __attribute__((ext_vector_type(4))) float fvec4;

#define INV2PI 0.15915494309189535f

__device__ __forceinline__ short f32_to_bf16_bits(float v) {
    __hip_bfloat16 hb = __float2bfloat16(v);
    short s;
    __builtin_memcpy(&s, &hb, 2);
    return s;
}

// Load the 4 x-values this thread needs for one K-step (column i of the x-tile).
__device__ __forceinline__ void loadx(float xv[4], const float* __restrict__ xbase,
                                      int arow_base, int i) {
#pragma unroll
    for (int jj = 0; jj < 4; ++jj)
        xv[jj] = xbase[(size_t)(jj * 64 + arow_base) * IDIM + i];
}

// Stage one K-step: trig->A_lds (bf16, swizzled), coeffs f32->bf16->B_lds (swizzled).
__device__ __forceinline__ void stage_step(const fvec4* __restrict__ bp,
                                           short* __restrict__ Ab, short* __restrict__ Bb,
                                           const float xv[4], float zq,
                                           int arow_base, int g0, int bo, int bh) {
    // B: 32 f32 per thread (half a row of the 256x64 f32 step-tile)
    fvec4 breg[8];
#pragma unroll
    for (int jj = 0; jj < 8; ++jj) breg[jj] = bp[jj];

    // A: 4 rows x 8 g-values of trig. val = cos(2*pi*(x*k/2pi - 0.25*z)) = cos/sin(x*k)
    float g0f = (float)g0;
#pragma unroll
    for (int jj = 0; jj < 4; ++jj) {
        int row = jj * 64 + arow_base;
        float rev = xv[jj] * INV2PI;
        float base = rev * g0f - zq;
        bhalf8 pack;
#pragma unroll
        for (int u = 0; u < 8; ++u) {
            float tv = __builtin_fmaf(rev, (float)(u + 1), base);
            tv = __builtin_amdgcn_fractf(tv);
            float c = __builtin_amdgcn_cosf(tv);
            pack[u] = f32_to_bf16_bits(c);
        }
        *(bhalf8*)((char*)Ab + (size_t)row * 128 + ((g0 * 2) ^ ((row & 7) << 4))) = pack;
    }

    // B: cvt 32 f32 -> 4x bhalf8, swizzled writes
#pragma unroll
    for (int jj = 0; jj < 4; ++jj) {
        bhalf8 pack;
#pragma unroll
        for (int u = 0; u < 8; ++u) {
            float v = breg[jj * 2 + (u >> 2)][u & 3];
            pack[u] = f32_to_bf16_bits(v);
        }
        *(bhalf8*)((char*)Bb + (size_t)bo * 128 + ((bh * 64 + jj * 16) ^ ((bo & 7) << 4))) = pack;
    }
}

__device__ __forceinline__ void compute_step(const short* __restrict__ Ab,
                                             const short* __restrict__ Bb,
                                             fvec4 acc[8][4],
                                             int lane, int wave_m, int wave_n) {
    int rA = wave_m * 128 + (lane & 15);
    int rB = wave_n * 64 + (lane & 15);
    int klane = (lane >> 4) * 16;        // 16B k-chunk per lane-quarter
    int msk = (lane & 7) << 4;           // swizzle XOR (row&7 == lane&7 for all frag rows)
#pragma unroll
    for (int ksub = 0; ksub < 2; ++ksub) {
        int kb = (ksub * 64 + klane) ^ msk;
        bhalf8 bfr[4];
#pragma unroll
        for (int fn = 0; fn < 4; ++fn)
            bfr[fn] = *(const bhalf8*)((const char*)Bb + (size_t)(rB + fn * 16) * 128 + kb);
#pragma unroll
        for (int fm = 0; fm < 8; ++fm) {
            bhalf8 afr = *(const bhalf8*)((const char*)Ab + (size_t)(rA + fm * 16) * 128 + kb);
#pragma unroll
            for (int fn = 0; fn < 4; ++fn)
                acc[fm][fn] = __builtin_amdgcn_mfma_f32_16x16x32_bf16(afr, bfr[fn], acc[fm][fn], 0, 0, 0);
        }
    }
}

__global__ void __launch_bounds__(512, 2)
fkan_gemm(const float* __restrict__ x, const float* __restrict__ coeffs,
          float* __restrict__ out) {
    __shared__ __align__(16) short A_lds[2][16384];   // 2 x 32KB
    __shared__ __align__(16) short B_lds[2][16384];   // 2 x 32KB

    // XCD-grouped block decode: blocks sharing a B-chunk land on one XCD's L2.
    int bx = blockIdx.x;              // 0..255
    int xcd = bx & 7;
    int j = bx >> 3;                  // 0..31
    int lg = xcd * 2 + (j & 1);       // logical group 0..15 = [ot|z|ks]
    int mt = j >> 1;                  // 0..15
    int ot = lg >> 3;                 // 0..1
    int z  = (lg >> 2) & 1;           // cos / sin
    int ks = lg & 3;                  // split-K chunk (64 i's each)
    int row0 = mt * 256, col0 = ot * 256;
    int i0 = ks * 64;
    float zq = z ? 0.25f : 0.0f;

    int t = threadIdx.x;
    int lane = t & 63, wid = t >> 6;
    int wave_m = wid & 1, wave_n = wid >> 1;

    // A staging: thread covers rows jj*64+arow_base, g-chunk g0..g0+7
    int arow_base = t >> 3;           // 0..63
    int g0 = (t & 7) * 8;             // 0..56
    // B staging: half-row bh of row bo
    int bo = t >> 1, bh = t & 1;

    const float* xbase = x + (size_t)row0 * IDIM;
    const fvec4* bpt = (const fvec4*)(coeffs + (size_t)z * ODIM * KDIM
                                      + (size_t)(col0 + bo) * KDIM + bh * 32);
    // per step i: bp = bpt + i*16 (64 floats)

    fvec4 acc[8][4];
#pragma unroll
    for (int a = 0; a < 8; ++a)
#pragma unroll
        for (int b = 0; b < 4; ++b) acc[a][b] = (fvec4)0.0f;

    float xv0[4], xv1[4];
    loadx(xv0, xbase, arow_base, i0);
    stage_step(bpt + (size_t)i0 * 16, A_lds[0], B_lds[0], xv0, zq, arow_base, g0, bo, bh);
    loadx(xv1, xbase, arow_base, i0 + 1);
    __syncthreads();

#pragma unroll 1
    for (int s2 = 0; s2 < 32; ++s2) {
        int i = i0 + 2 * s2;
        bool more = (s2 < 31);
        // even step: compute buf0, stage i+1 -> buf1
        stage_step(bpt + (size_t)(i + 1) * 16, A_lds[1], B_lds[1], xv1, zq, arow_base, g0, bo, bh);
        if (more) loadx(xv0, xbase, arow_base, i + 2);
        compute_step(A_lds[0], B_lds[0], acc, lane, wave_m, wave_n);
        __syncthreads();
        // odd step: compute buf1, stage i+2 -> buf0
        if (more) {
            stage_step(bpt + (size_t)(i + 2) * 16, A_lds[0], B_lds[0], xv0, zq, arow_base, g0, bo, bh);
            loadx(xv1, xbase, arow_base, i + 3);
        }
        compute_step(A_lds[1], B_lds[1], acc, lane, wave_m, wave_n);
        __syncthreads();
    }

    // epilogue: C/D layout col=lane&15, row=(lane>>4)*4+r
#pragma unroll
    for (int fm = 0; fm < 8; ++fm) {
#pragma unroll
        for (int fn = 0; fn < 4; ++fn) {
            int col = col0 + wave_n * 64 + fn * 16 + (lane & 15);
#pragma unroll
            for (int r = 0; r < 4; ++r) {
                int row = row0 + wave_m * 128 + fm * 16 + ((lane >> 4) * 4) + r;
                atomicAdd(&out[(size_t)row * ODIM + col], acc[fm][fn][r]);
            }
        }
    }
}

__global__ void bias_init(const float* __restrict__ bias, float* __restrict__ out) {
    int idx = blockIdx.x * 256 + threadIdx.x;          // over 2M/4 f32x4
    fvec4 bv = ((const fvec4*)bias)[idx & 127];        // 128 f32x4 per output row
    ((fvec4*)out)[idx] = bv;
}

extern "C" void kernel_launch(void* const* d_in, const int* in_sizes, int n_in,
                              void* d_out, int out_size, void* d_ws, size_t ws_size,
                              hipStream_t stream) {
    (void)in_sizes; (void)n_in; (void)d_ws; (void)ws_size; (void)out_size;
    const float* x      = (const float*)d_in[0];
    const float* coeffs = (const float*)d_in[1];
    const float* bias   = (const float*)d_in[2];
    float* out = (float*)d_out;

    // out = bias (broadcast), then all 256 GEMM blocks atomicAdd their partials.
    bias_init<<<dim3(2048), dim3(256), 0, stream>>>(bias, out);
    fkan_gemm<<<dim3(256), dim3(512), 0, stream>>>(x, coeffs, out);
}